// Round 10
// baseline (286.760 us; speedup 1.0000x reference)
//
#include <hip/hip_runtime.h>

#define NB 2048
#define S_ 200
#define C_ 25
#define H_ 8
#define WROWS 208        // padded row count for packed X rows
#define STR 28           // dword stride of packed rows (b128-aligned; 28 ≡ -4 mod 32, same bank behavior as 36)
#define NSTRIP 13        // ceil(200/16) t-strips
#define NSTILE 13        // ceil(200/16) s-tiles
#define NPAIR 7          // ceil(13/2) strip pairs (K=32 each)
#define XDS 28           // x_del float stride in reused LDS (= STR)
#define WFRAG (13 * 64 * 4)   // 3328 dwords per W fragment plane

typedef __bf16   bf16x8 __attribute__((ext_vector_type(8)));
typedef float    f32x4  __attribute__((ext_vector_type(4)));
typedef unsigned uint4v __attribute__((ext_vector_type(4)));

struct Frag { bf16x8 hi, lo; };

__device__ __forceinline__ unsigned short f2bf(float f) {
    unsigned u = __builtin_bit_cast(unsigned, f);
    return (unsigned short)((u + 0x7FFFu + ((u >> 16) & 1u)) >> 16);
}
__device__ __forceinline__ float bfh2f(unsigned short h) {
    return __builtin_bit_cast(float, (unsigned)h << 16);
}
__device__ __forceinline__ unsigned hi_pair(unsigned d0, unsigned d1) {
    return (d0 & 0xFFFFu) | (d1 << 16);
}
__device__ __forceinline__ unsigned lo_pair(unsigned d0, unsigned d1) {
    return (d0 >> 16) | (d1 & 0xFFFF0000u);
}
__device__ __forceinline__ Frag build_frag8(uint4v d0, uint4v d1) {
    uint4v h, l;
    h.x = hi_pair(d0.x, d0.y); h.y = hi_pair(d0.z, d0.w);
    h.z = hi_pair(d1.x, d1.y); h.w = hi_pair(d1.z, d1.w);
    l.x = lo_pair(d0.x, d0.y); l.y = lo_pair(d0.z, d0.w);
    l.z = lo_pair(d1.x, d1.y); l.w = lo_pair(d1.z, d1.w);
    Frag f;
    f.hi = __builtin_bit_cast(bf16x8, h);
    f.lo = __builtin_bit_cast(bf16x8, l);
    return f;
}
__device__ __forceinline__ bf16x8 build_hi8(uint4v d0, uint4v d1) {
    uint4v h;
    h.x = hi_pair(d0.x, d0.y); h.y = hi_pair(d0.z, d0.w);
    h.z = hi_pair(d1.x, d1.y); h.w = hi_pair(d1.z, d1.w);
    return __builtin_bit_cast(bf16x8, h);
}
__device__ __forceinline__ f32x4 mfma16(bf16x8 a, bf16x8 b, f32x4 c) {
    return __builtin_amdgcn_mfma_f32_16x16x32_bf16(a, b, c, 0, 0, 0);
}
// split-precision D += A*B (drop lo*lo term)
__device__ __forceinline__ f32x4 mfma_split(const Frag& a, const Frag& b, f32x4 c) {
    c = mfma16(a.hi, b.hi, c);
    c = mfma16(a.hi, b.lo, c);
    c = mfma16(a.lo, b.hi, c);
    return c;
}
// raw transcendentals: v_exp_f32 is 2^x, v_log_f32 is log2(x)
__device__ __forceinline__ float fexp2(float x) {
    float r; asm("v_exp_f32 %0, %1" : "=v"(r) : "v"(x)); return r;
}
__device__ __forceinline__ float flog2(float x) {
    float r; asm("v_log_f32 %0, %1" : "=v"(r) : "v"(x)); return r;
}
// pack two f32 -> (bf16(lo) | bf16(hi)<<16), RNE (no builtin on gfx950)
__device__ __forceinline__ unsigned cvt_pk_bf16(float vlo, float vhi) {
    unsigned r; asm("v_cvt_pk_bf16_f32 %0, %1, %2" : "=v"(r) : "v"(vlo), "v"(vhi)); return r;
}
__device__ __forceinline__ float lo16f(unsigned p) { return __builtin_bit_cast(float, p << 16); }
__device__ __forceinline__ float hi16f(unsigned p) { return __builtin_bit_cast(float, p & 0xFFFF0000u); }
// pack two f32 into two per-value (hi|lo<<16) dwords via cvt_pk (cheaper than 2x scalar pack)
__device__ __forceinline__ void pack_hl2(float v0, float v1, unsigned& d0, unsigned& d1) {
    unsigned hp = cvt_pk_bf16(v0, v1);
    float r0 = v0 - lo16f(hp);
    float r1 = v1 - hi16f(hp);
    unsigned lp = cvt_pk_bf16(r0, r1);
    d0 = (hp & 0xFFFFu) | (lp << 16);
    d1 = (hp >> 16) | (lp & 0xFFFF0000u);
}

// In-register MFMA C-layout (rows on quads/regs) -> A-layout (k on quads) transpose.
__device__ __forceinline__ void xpose_quads(unsigned& a0, unsigned& a1,
                                            unsigned& b0, unsigned& b1) {
    asm("v_permlane32_swap_b32 %0, %1" : "+v"(a0), "+v"(b0));
    asm("v_permlane32_swap_b32 %0, %1" : "+v"(a1), "+v"(b1));
    asm("v_permlane16_swap_b32 %0, %1" : "+v"(a0), "+v"(b0));
    asm("v_permlane16_swap_b32 %0, %1" : "+v"(a1), "+v"(b1));
}

// B2 fragment gather (X^T columns). GUARD only needed for pair==6 (t2 can reach 223>=WROWS).
template<bool GUARD>
__device__ __forceinline__ void build_b2h(const unsigned* X32p, int pair, int q, int n,
                                          bf16x8 b2h[2]) {
#pragma unroll
    for (int ct = 0; ct < 2; ++ct) {
        const int c = ct * 16 + n;
        uint4v d0, d1;
#pragma unroll
        for (int j = 0; j < 4; ++j) {
            int t2 = pair * 32 + q * 8 + j;
            unsigned v;
            if (GUARD) v = (t2 < WROWS) ? X32p[t2 * STR + c] : 0u;
            else       v = X32p[t2 * STR + c];
            ((unsigned*)&d0)[j] = v;
        }
#pragma unroll
        for (int j = 0; j < 4; ++j) {
            int t2 = pair * 32 + q * 8 + 4 + j;
            unsigned v;
            if (GUARD) v = (t2 < WROWS) ? X32p[t2 * STR + c] : 0u;
            else       v = X32p[t2 * STR + c];
            ((unsigned*)&d1)[j] = v;
        }
        b2h[ct] = build_hi8(d0, d1);
    }
}

// ---------- prep kernel: W fragment planes (pre-scaled by log2e) + A^2, A^4, A^8 ----------
__global__ void prep_w_kernel(const float* __restrict__ delay_W,
                              const float* __restrict__ A_W,
                              unsigned* __restrict__ ws) {
    const float LOG2E = 1.44269504088896340736f;
    unsigned* Whi = ws;
    unsigned* Wlo = ws + WFRAG;
    for (int idx = blockIdx.x * 256 + threadIdx.x; idx < WFRAG; idx += gridDim.x * 256) {
        int d = idx & 3, lane = (idx >> 2) & 63, sv = idx >> 8;
        int q = lane >> 4, nn = lane & 15;
        int s  = sv * 16 + nn;
        int c0 = q * 8 + 2 * d;
        float v0 = (s < S_ && c0     < C_) ? delay_W[s * C_ + c0]     * LOG2E : 0.f;
        float v1 = (s < S_ && c0 + 1 < C_) ? delay_W[s * C_ + c0 + 1] * LOG2E : 0.f;
        unsigned short h0 = f2bf(v0), h1 = f2bf(v1);
        unsigned short l0 = f2bf(v0 - bfh2f(h0)), l1 = f2bf(v1 - bfh2f(h1));
        Whi[idx] = (unsigned)h0 | ((unsigned)h1 << 16);
        Wlo[idx] = (unsigned)l0 | ((unsigned)l1 << 16);
    }
    // A^2, A^4, A^8 for the 8-step parallel recurrence
    __shared__ float A2s[64];
    __shared__ float A4s[64];
    if (blockIdx.x == 0) {
        float* A2g = (float*)(ws + 2 * WFRAG);
        float* A4g = (float*)(ws + 2 * WFRAG + 64);
        float* A8g = (float*)(ws + 2 * WFRAG + 128);
        const int i = threadIdx.x >> 3, j = threadIdx.x & 7;
        if (threadIdx.x < 64) {
            float s = 0.f;
            for (int k = 0; k < 8; ++k) s = fmaf(A_W[i * 8 + k], A_W[k * 8 + j], s);
            A2s[threadIdx.x] = s; A2g[threadIdx.x] = s;
        }
        __syncthreads();
        if (threadIdx.x < 64) {
            float s = 0.f;
            for (int k = 0; k < 8; ++k) s = fmaf(A2s[i * 8 + k], A2s[k * 8 + j], s);
            A4s[threadIdx.x] = s; A4g[threadIdx.x] = s;
        }
        __syncthreads();
        if (threadIdx.x < 64) {
            float s = 0.f;
            for (int k = 0; k < 8; ++k) s = fmaf(A4s[i * 8 + k], A4s[k * 8 + j], s);
            A8g[threadIdx.x] = s;
        }
    }
}

// ---------- main kernel: one block per batch ----------
__global__ __launch_bounds__(256, 6) void ssm_syn_delay_kernel(
    const float* __restrict__ x,       const unsigned* __restrict__ ws,
    const float* __restrict__ delay_b, const float* __restrict__ U_W,
    const float* __restrict__ U_b,     const float* __restrict__ A_W,
    const float* __restrict__ B_W,     const float* __restrict__ B_b,
    const float* __restrict__ out_W,   const float* __restrict__ out_b,
    float* __restrict__ out)
{
    // 24,976 B total -> 6 blocks/CU (24 waves)
    __shared__ __align__(16) unsigned X32[WROWS * STR + 4]; // 23,312 B (+4 dw pad for q=3 tail reads)
    __shared__ __align__(16) float lsed[WROWS];             //    832 B (log2-domain lse)
    __shared__ __align__(16) float dbs_l[WROWS];            //    832 B (delay_b * log2e; -inf pad)

    const int tid  = threadIdx.x;
    const int wid  = tid >> 6;
    const int lane = tid & 63;
    const int q    = lane >> 4;     // quad 0..3
    const int n    = lane & 15;     // col-lane 0..15
    const int b    = blockIdx.x;
    const float* xb = x + (size_t)b * (S_ * C_);
    const unsigned* Whi = ws;
    const unsigned* Wlo = ws + WFRAG;
    const float* A2g = (const float*)(ws + 2 * WFRAG);
    const float* A4g = (const float*)(ws + 2 * WFRAG + 64);
    const float* A8g = (const float*)(ws + 2 * WFRAG + 128);

    // ---- Phase 0: stage packed x rows (vectorized, cvt_pk) + delay_b into LDS ----
    for (int i = tid; i < WROWS * 7; i += 256) {
        int r = i / 7, cg = i - r * 7;        // cg: group of 4 dwords in the 28-dword row
        f32x4 v = {0.f, 0.f, 0.f, 0.f};
        if (r < S_) {
            if (cg < 6)       __builtin_memcpy(&v, &xb[r * C_ + cg * 4], 16); // c 0..23
            else              v[0] = xb[r * C_ + 24];                          // c 24 (tail)
        }
        unsigned e0, e1, e2, e3;
        pack_hl2(v[0], v[1], e0, e1);
        pack_hl2(v[2], v[3], e2, e3);
        uint4v p = {e0, e1, e2, e3};
        *(uint4v*)&X32[r * STR + cg * 4] = p;
    }
    // CRITICAL: zero the 4 tail-pad dwords. Row 207's q=3 fragment read covers
    // dwords 5824..5827; uninitialized LDS there can hold bf16-NaN patterns and
    // MFMA NaN*0 = NaN poisons lse[207] -> P -> x_del (R9 failure).
    if (tid == 0) {
        uint4v z = {0u, 0u, 0u, 0u};
        *(uint4v*)&X32[WROWS * STR] = z;
    }
    for (int i = tid; i < WROWS; i += 256)
        dbs_l[i] = (i < S_) ? delay_b[i] * 1.44269504088896340736f : -1e30f;
    __syncthreads();

    // ---- Pass 1: lse[t] (log2 domain) via MFMA. Wave owns t-strips wid, wid+4, ... ----
    for (int st = wid; st < NSTRIP; st += 4) {
        const int t = st * 16 + n;
        const uint4v* xp = (const uint4v*)&X32[t * STR + q * 8];
        Frag fa = build_frag8(xp[0], xp[1]);       // A[m=t][k=c] (k>=25: junk x W-zeros = 0)
        float rs0 = 0.f, rs1 = 0.f, rs2 = 0.f, rs3 = 0.f;
        for (int sv = 0; sv < NSTILE; ++sv) {
            Frag fb;                               // B[k=c][n=s], pre-laid-out fragments
            fb.hi = __builtin_bit_cast(bf16x8, *(const uint4v*)&Whi[(sv * 64 + lane) * 4]);
            fb.lo = __builtin_bit_cast(bf16x8, *(const uint4v*)&Wlo[(sv * 64 + lane) * 4]);
            f32x4 L = {0.f, 0.f, 0.f, 0.f};
            L = mfma_split(fa, fb, L);
            const float dbv = dbs_l[sv * 16 + n];  // = -1e30 for padded s -> exp2 = 0
            rs0 += fexp2(L[0] + dbv);
            rs1 += fexp2(L[1] + dbv);
            rs2 += fexp2(L[2] + dbv);
            rs3 += fexp2(L[3] + dbv);
        }
#pragma unroll
        for (int off = 1; off < 16; off <<= 1) {
            rs0 += __shfl_xor(rs0, off);
            rs1 += __shfl_xor(rs1, off);
            rs2 += __shfl_xor(rs2, off);
            rs3 += __shfl_xor(rs3, off);
        }
        if (n < 4) {
            float v = (n == 0) ? rs0 : (n == 1) ? rs1 : (n == 2) ? rs2 : rs3;
            lsed[st * 16 + q * 4 + n] = flog2(v);
        }
    }
    __syncthreads();

    // ---- Pass 2: x_del = P^T X via MFMA, strip pairs; P transpose fully in-register ----
    f32x4 acc[4][2];
#pragma unroll
    for (int i = 0; i < 4; ++i)
#pragma unroll
        for (int j = 0; j < 2; ++j) acc[i][j] = f32x4{0.f, 0.f, 0.f, 0.f};

    for (int pair = 0; pair < NPAIR; ++pair) {
        const int sA = 2 * pair, sB = sA + 1;
        const bool bval = (sB < NSTRIP);
        const uint4v* xpA = (const uint4v*)&X32[(sA * 16 + n) * STR + q * 8];
        Frag faA = build_frag8(xpA[0], xpA[1]);
        Frag faB;
        if (bval) {
            const uint4v* xpB = (const uint4v*)&X32[(sB * 16 + n) * STR + q * 8];
            faB = build_frag8(xpB[0], xpB[1]);
        }
        f32x4 lseA = *(const f32x4*)&lsed[sA * 16 + q * 4];
        f32x4 lseB = bval ? *(const f32x4*)&lsed[sB * 16 + q * 4] : f32x4{0,0,0,0};
        // B2 frags (hi only): B[k=t][n=c], t = pair*32 + q*8 + j
        bf16x8 b2h[2];
        if (pair < 6) build_b2h<false>(X32, pair, q, n, b2h);
        else          build_b2h<true >(X32, pair, q, n, b2h);

#pragma unroll
        for (int si = 0; si < 4; ++si) {
            const int sv = wid + 4 * si;
            if (sv >= NSTILE) continue;          // wave-uniform branch
            Frag fb;
            fb.hi = __builtin_bit_cast(bf16x8, *(const uint4v*)&Whi[(sv * 64 + lane) * 4]);
            fb.lo = __builtin_bit_cast(bf16x8, *(const uint4v*)&Wlo[(sv * 64 + lane) * 4]);
            const float dbv = dbs_l[sv * 16 + n];
            // strip A logits -> P (hi/lo packed pairs, C-layout)
            unsigned pA0, pA1, qA0, qA1;
            {
                f32x4 L = {0.f, 0.f, 0.f, 0.f};
                L = mfma_split(faA, fb, L);
                float e0 = fexp2(L[0] + dbv - lseA[0]);
                float e1 = fexp2(L[1] + dbv - lseA[1]);
                float e2 = fexp2(L[2] + dbv - lseA[2]);
                float e3 = fexp2(L[3] + dbv - lseA[3]);
                pA0 = cvt_pk_bf16(e0, e1);
                pA1 = cvt_pk_bf16(e2, e3);
                qA0 = cvt_pk_bf16(e0 - lo16f(pA0), e1 - hi16f(pA0));
                qA1 = cvt_pk_bf16(e2 - lo16f(pA1), e3 - hi16f(pA1));
            }
            // strip B (or zeros)
            unsigned pB0 = 0u, pB1 = 0u, qB0 = 0u, qB1 = 0u;
            if (bval) {
                f32x4 L = {0.f, 0.f, 0.f, 0.f};
                L = mfma_split(faB, fb, L);
                float e0 = fexp2(L[0] + dbv - lseB[0]);
                float e1 = fexp2(L[1] + dbv - lseB[1]);
                float e2 = fexp2(L[2] + dbv - lseB[2]);
                float e3 = fexp2(L[3] + dbv - lseB[3]);
                pB0 = cvt_pk_bf16(e0, e1);
                pB1 = cvt_pk_bf16(e2, e3);
                qB0 = cvt_pk_bf16(e0 - lo16f(pB0), e1 - hi16f(pB0));
                qB1 = cvt_pk_bf16(e2 - lo16f(pB1), e3 - hi16f(pB1));
            }
            // in-register transpose to A-layout: A[m=s][k=t], k = q*8 + j
            xpose_quads(pA0, pA1, pB0, pB1);
            xpose_quads(qA0, qA1, qB0, qB1);
            uint4v hv = {pA0, pA1, pB0, pB1};
            uint4v lv = {qA0, qA1, qB0, qB1};
            bf16x8 a2h = __builtin_bit_cast(bf16x8, hv);
            bf16x8 a2l = __builtin_bit_cast(bf16x8, lv);
#pragma unroll
            for (int ct = 0; ct < 2; ++ct) {
                f32x4 c4 = acc[si][ct];
                c4 = mfma16(a2h, b2h[ct], c4);
                c4 = mfma16(a2l, b2h[ct], c4);
                acc[si][ct] = c4;
            }
        }
    }
    __syncthreads();   // all X32 reads done; safe to alias

    // ---- store x_del into reused LDS (float, stride XDS=28, 16B-aligned rows) ----
    float* fbse = (float*)&X32[0];
    float* xdelf = fbse;            // x_del: [0 .. 5600)
    float* pbuf  = fbse;            // R0 [0..1600): p_s, later p4
    float* r1    = fbse + 1600;     // R1 [1600..3200): p1, later h
    float* r2    = fbse + 3200;     // R2 [3200..4800): p2
#pragma unroll
    for (int si = 0; si < 4; ++si) {
        const int sv = wid + 4 * si;
        if (sv >= NSTILE) continue;
#pragma unroll
        for (int ct = 0; ct < 2; ++ct) {
            const int c = ct * 16 + n;
            if (c < C_) {
#pragma unroll
                for (int r = 0; r < 4; ++r) {
                    const int s = sv * 16 + q * 4 + r;
                    if (s < S_) xdelf[s * XDS + c] = acc[si][ct][r];
                }
            }
        }
    }
    __syncthreads();

    // ---- u / bgate epilogue: load row into regs, barrier, then write p into R0 ----
    {
        float a[24], a24 = 0.f;
        const bool act = tid < S_;
        if (act) {
            const f32x4* ar = (const f32x4*)&xdelf[tid * XDS];
#pragma unroll
            for (int k = 0; k < 6; ++k) *(f32x4*)&a[k * 4] = ar[k];
            a24 = xdelf[tid * XDS + 24];
        }
        __syncthreads();              // all x_del rows consumed; R0 write is safe
        if (act) {
            const int s = tid;
#pragma unroll
            for (int h = 0; h < H_; ++h) {
                float uu = fmaf(a24, U_W[h * C_ + 24], U_b[h]);
                float bb = fmaf(a24, B_W[h * C_ + 24], B_b[h]);
#pragma unroll
                for (int i = 0; i < 24; ++i) {
                    uu = fmaf(a[i], U_W[h * C_ + i], uu);
                    bb = fmaf(a[i], B_W[h * C_ + i], bb);
                }
                float sg_ = 1.0f / (1.0f + __expf(-bb));
                pbuf[s * H_ + h] = uu * sg_;
            }
        }
    }
    __syncthreads();

    // ---- linear recurrence h_s = A h_{s-1} + p_s via 8-step parallel prefix ----
    // p1 = A p[s-1] + p[s]   R0 -> R1
    for (int i2 = tid; i2 < S_ * H_; i2 += 256) {
        const int s = i2 >> 3, i = i2 & 7;
        float v = pbuf[i2];
        if (s > 0) {
            const float* pm = &pbuf[(s - 1) * H_];
#pragma unroll
            for (int j = 0; j < H_; ++j) v = fmaf(A_W[i * H_ + j], pm[j], v);
        }
        r1[i2] = v;
    }
    __syncthreads();
    // p2 = A^2 p1[s-2] + p1[s]   R1 -> R2
    for (int i2 = tid; i2 < S_ * H_; i2 += 256) {
        const int s = i2 >> 3, i = i2 & 7;
        float v = r1[i2];
        if (s > 1) {
            const float* pm = &r1[(s - 2) * H_];
#pragma unroll
            for (int j = 0; j < H_; ++j) v = fmaf(A2g[i * H_ + j], pm[j], v);
        }
        r2[i2] = v;
    }
    __syncthreads();
    // p4 = A^4 p2[s-4] + p2[s]   R2 -> R0
    for (int i2 = tid; i2 < S_ * H_; i2 += 256) {
        const int s = i2 >> 3, i = i2 & 7;
        float v = r2[i2];
        if (s > 3) {
            const float* pm = &r2[(s - 4) * H_];
#pragma unroll
            for (int j = 0; j < H_; ++j) v = fmaf(A4g[i * H_ + j], pm[j], v);
        }
        pbuf[i2] = v;
    }
    __syncthreads();
    // 8 independent chains (s mod 8) of 25 steps; 64 lanes of wave 0; h -> R1
    if (tid < 64) {
        const int r = tid >> 3, i = tid & 7;
        float A8r[H_];
#pragma unroll
        for (int j = 0; j < H_; ++j) A8r[j] = A8g[i * H_ + j];
        float h = 0.f;
        for (int k = 0; k < 25; ++k) {
            const int s = 8 * k + r;
            float v = pbuf[s * H_ + i];
#pragma unroll
            for (int j = 0; j < H_; ++j) v = fmaf(A8r[j], __shfl(h, j, 8), v);
            h = v;
            r1[s * H_ + i] = h;
        }
    }
    __syncthreads();

    // ---- out[b,s,c] = hs[s]·out_W[c,:] + out_b[c] (vectorized loads, h in R1) ----
    float* ob_ptr = out + (size_t)b * (S_ * C_);
    for (int i = tid; i < S_ * C_; i += 256) {
        int s = i / C_, c = i - s * C_;
        const f32x4* pr = (const f32x4*)&r1[s * H_];
        const f32x4* wr = (const f32x4*)&out_W[c * H_];
        f32x4 h0 = pr[0], h1 = pr[1];
        f32x4 w0 = wr[0], w1 = wr[1];
        float v = out_b[c];
        v = fmaf(h0[0], w0[0], v);
        v = fmaf(h0[1], w0[1], v);
        v = fmaf(h0[2], w0[2], v);
        v = fmaf(h0[3], w0[3], v);
        v = fmaf(h1[0], w1[0], v);
        v = fmaf(h1[1], w1[1], v);
        v = fmaf(h1[2], w1[2], v);
        v = fmaf(h1[3], w1[3], v);
        ob_ptr[i] = v;
    }
}

extern "C" void kernel_launch(void* const* d_in, const int* in_sizes, int n_in,
                              void* d_out, int out_size, void* d_ws, size_t ws_size,
                              hipStream_t stream) {
    const float* x       = (const float*)d_in[0];
    const float* delay_W = (const float*)d_in[1];
    const float* delay_b = (const float*)d_in[2];
    const float* U_W     = (const float*)d_in[3];
    const float* U_b     = (const float*)d_in[4];
    const float* A_W     = (const float*)d_in[5];
    const float* B_W     = (const float*)d_in[6];
    const float* B_b     = (const float*)d_in[7];
    const float* out_W   = (const float*)d_in[8];
    const float* out_b   = (const float*)d_in[9];
    float* out = (float*)d_out;
    unsigned* ws = (unsigned*)d_ws;   // (2*3328 + 192) dwords = 27,392 B

    prep_w_kernel<<<4, 256, 0, stream>>>(delay_W, A_W, ws);
    ssm_syn_delay_kernel<<<NB, 256, 0, stream>>>(
        x, ws, delay_b, U_W, U_b, A_W, B_W, B_b, out_W, out_b, out);
}

// Round 11
// 231.117 us; speedup vs baseline: 1.2408x; 1.2408x over previous
//
#include <hip/hip_runtime.h>

#define NB 2048
#define S_ 200
#define C_ 25
#define H_ 8
#define WROWS 208        // padded row count for packed X rows
#define STR 28           // dword stride of packed rows (b128-aligned; 28 ≡ -4 mod 32, same bank behavior as 36)
#define NSTRIP 13        // ceil(200/16) t-strips
#define NSTILE 13        // ceil(200/16) s-tiles
#define NPAIR 7          // ceil(13/2) strip pairs (K=32 each)
#define XDS 28           // x_del float stride in reused LDS (= STR)
#define WFRAG (13 * 64 * 4)   // 3328 dwords per W fragment plane

typedef __bf16   bf16x8 __attribute__((ext_vector_type(8)));
typedef float    f32x4  __attribute__((ext_vector_type(4)));
typedef unsigned uint4v __attribute__((ext_vector_type(4)));

struct Frag { bf16x8 hi, lo; };

__device__ __forceinline__ unsigned short f2bf(float f) {
    unsigned u = __builtin_bit_cast(unsigned, f);
    return (unsigned short)((u + 0x7FFFu + ((u >> 16) & 1u)) >> 16);
}
__device__ __forceinline__ float bfh2f(unsigned short h) {
    return __builtin_bit_cast(float, (unsigned)h << 16);
}
__device__ __forceinline__ unsigned hi_pair(unsigned d0, unsigned d1) {
    return (d0 & 0xFFFFu) | (d1 << 16);
}
__device__ __forceinline__ unsigned lo_pair(unsigned d0, unsigned d1) {
    return (d0 >> 16) | (d1 & 0xFFFF0000u);
}
__device__ __forceinline__ Frag build_frag8(uint4v d0, uint4v d1) {
    uint4v h, l;
    h.x = hi_pair(d0.x, d0.y); h.y = hi_pair(d0.z, d0.w);
    h.z = hi_pair(d1.x, d1.y); h.w = hi_pair(d1.z, d1.w);
    l.x = lo_pair(d0.x, d0.y); l.y = lo_pair(d0.z, d0.w);
    l.z = lo_pair(d1.x, d1.y); l.w = lo_pair(d1.z, d1.w);
    Frag f;
    f.hi = __builtin_bit_cast(bf16x8, h);
    f.lo = __builtin_bit_cast(bf16x8, l);
    return f;
}
__device__ __forceinline__ bf16x8 build_hi8(uint4v d0, uint4v d1) {
    uint4v h;
    h.x = hi_pair(d0.x, d0.y); h.y = hi_pair(d0.z, d0.w);
    h.z = hi_pair(d1.x, d1.y); h.w = hi_pair(d1.z, d1.w);
    return __builtin_bit_cast(bf16x8, h);
}
__device__ __forceinline__ f32x4 mfma16(bf16x8 a, bf16x8 b, f32x4 c) {
    return __builtin_amdgcn_mfma_f32_16x16x32_bf16(a, b, c, 0, 0, 0);
}
// split-precision D += A*B (drop lo*lo term)
__device__ __forceinline__ f32x4 mfma_split(const Frag& a, const Frag& b, f32x4 c) {
    c = mfma16(a.hi, b.hi, c);
    c = mfma16(a.hi, b.lo, c);
    c = mfma16(a.lo, b.hi, c);
    return c;
}
// raw transcendentals: v_exp_f32 is 2^x, v_log_f32 is log2(x)
__device__ __forceinline__ float fexp2(float x) {
    float r; asm("v_exp_f32 %0, %1" : "=v"(r) : "v"(x)); return r;
}
__device__ __forceinline__ float flog2(float x) {
    float r; asm("v_log_f32 %0, %1" : "=v"(r) : "v"(x)); return r;
}
// pack two f32 -> (bf16(lo) | bf16(hi)<<16), RNE (no builtin on gfx950)
__device__ __forceinline__ unsigned cvt_pk_bf16(float vlo, float vhi) {
    unsigned r; asm("v_cvt_pk_bf16_f32 %0, %1, %2" : "=v"(r) : "v"(vlo), "v"(vhi)); return r;
}
__device__ __forceinline__ float lo16f(unsigned p) { return __builtin_bit_cast(float, p << 16); }
__device__ __forceinline__ float hi16f(unsigned p) { return __builtin_bit_cast(float, p & 0xFFFF0000u); }
// pack two f32 into two per-value (hi|lo<<16) dwords via cvt_pk (cheaper than 2x scalar pack)
__device__ __forceinline__ void pack_hl2(float v0, float v1, unsigned& d0, unsigned& d1) {
    unsigned hp = cvt_pk_bf16(v0, v1);
    float r0 = v0 - lo16f(hp);
    float r1 = v1 - hi16f(hp);
    unsigned lp = cvt_pk_bf16(r0, r1);
    d0 = (hp & 0xFFFFu) | (lp << 16);
    d1 = (hp >> 16) | (lp & 0xFFFF0000u);
}

// In-register MFMA C-layout (rows on quads/regs) -> A-layout (k on quads) transpose.
__device__ __forceinline__ void xpose_quads(unsigned& a0, unsigned& a1,
                                            unsigned& b0, unsigned& b1) {
    asm("v_permlane32_swap_b32 %0, %1" : "+v"(a0), "+v"(b0));
    asm("v_permlane32_swap_b32 %0, %1" : "+v"(a1), "+v"(b1));
    asm("v_permlane16_swap_b32 %0, %1" : "+v"(a0), "+v"(b0));
    asm("v_permlane16_swap_b32 %0, %1" : "+v"(a1), "+v"(b1));
}

// B2 fragment gather (X^T columns). GUARD only needed for pair==6 (t2 can reach 223>=WROWS).
template<bool GUARD>
__device__ __forceinline__ void build_b2h(const unsigned* X32p, int pair, int q, int n,
                                          bf16x8 b2h[2]) {
#pragma unroll
    for (int ct = 0; ct < 2; ++ct) {
        const int c = ct * 16 + n;
        uint4v d0, d1;
#pragma unroll
        for (int j = 0; j < 4; ++j) {
            int t2 = pair * 32 + q * 8 + j;
            unsigned v;
            if (GUARD) v = (t2 < WROWS) ? X32p[t2 * STR + c] : 0u;
            else       v = X32p[t2 * STR + c];
            ((unsigned*)&d0)[j] = v;
        }
#pragma unroll
        for (int j = 0; j < 4; ++j) {
            int t2 = pair * 32 + q * 8 + 4 + j;
            unsigned v;
            if (GUARD) v = (t2 < WROWS) ? X32p[t2 * STR + c] : 0u;
            else       v = X32p[t2 * STR + c];
            ((unsigned*)&d1)[j] = v;
        }
        b2h[ct] = build_hi8(d0, d1);
    }
}

// ---------- prep kernel: W fragment planes (pre-scaled by log2e) + A^2, A^4, A^8 ----------
__global__ void prep_w_kernel(const float* __restrict__ delay_W,
                              const float* __restrict__ A_W,
                              unsigned* __restrict__ ws) {
    const float LOG2E = 1.44269504088896340736f;
    unsigned* Whi = ws;
    unsigned* Wlo = ws + WFRAG;
    for (int idx = blockIdx.x * 256 + threadIdx.x; idx < WFRAG; idx += gridDim.x * 256) {
        int d = idx & 3, lane = (idx >> 2) & 63, sv = idx >> 8;
        int q = lane >> 4, nn = lane & 15;
        int s  = sv * 16 + nn;
        int c0 = q * 8 + 2 * d;
        float v0 = (s < S_ && c0     < C_) ? delay_W[s * C_ + c0]     * LOG2E : 0.f;
        float v1 = (s < S_ && c0 + 1 < C_) ? delay_W[s * C_ + c0 + 1] * LOG2E : 0.f;
        unsigned short h0 = f2bf(v0), h1 = f2bf(v1);
        unsigned short l0 = f2bf(v0 - bfh2f(h0)), l1 = f2bf(v1 - bfh2f(h1));
        Whi[idx] = (unsigned)h0 | ((unsigned)h1 << 16);
        Wlo[idx] = (unsigned)l0 | ((unsigned)l1 << 16);
    }
    // A^2, A^4, A^8 for the 8-step parallel recurrence
    __shared__ float A2s[64];
    __shared__ float A4s[64];
    if (blockIdx.x == 0) {
        float* A2g = (float*)(ws + 2 * WFRAG);
        float* A4g = (float*)(ws + 2 * WFRAG + 64);
        float* A8g = (float*)(ws + 2 * WFRAG + 128);
        const int i = threadIdx.x >> 3, j = threadIdx.x & 7;
        if (threadIdx.x < 64) {
            float s = 0.f;
            for (int k = 0; k < 8; ++k) s = fmaf(A_W[i * 8 + k], A_W[k * 8 + j], s);
            A2s[threadIdx.x] = s; A2g[threadIdx.x] = s;
        }
        __syncthreads();
        if (threadIdx.x < 64) {
            float s = 0.f;
            for (int k = 0; k < 8; ++k) s = fmaf(A2s[i * 8 + k], A2s[k * 8 + j], s);
            A4s[threadIdx.x] = s; A4g[threadIdx.x] = s;
        }
        __syncthreads();
        if (threadIdx.x < 64) {
            float s = 0.f;
            for (int k = 0; k < 8; ++k) s = fmaf(A4s[i * 8 + k], A4s[k * 8 + j], s);
            A8g[threadIdx.x] = s;
        }
    }
}

// ---------- main kernel: one block per batch ----------
// NOTE: min-waves bound stays at 5 (allocator headroom ~102 regs incl. AGPR).
// Occupancy comes from LDS (24,976 B -> 6 blocks/CU) as long as natural
// allocation stays <= 85 regs; forcing 6 via launch_bounds caused R10's spills.
__global__ __launch_bounds__(256, 5) void ssm_syn_delay_kernel(
    const float* __restrict__ x,       const unsigned* __restrict__ ws,
    const float* __restrict__ delay_b, const float* __restrict__ U_W,
    const float* __restrict__ U_b,     const float* __restrict__ A_W,
    const float* __restrict__ B_W,     const float* __restrict__ B_b,
    const float* __restrict__ out_W,   const float* __restrict__ out_b,
    float* __restrict__ out)
{
    // 24,976 B total -> 6 blocks/CU (24 waves) via LDS limit
    __shared__ __align__(16) unsigned X32[WROWS * STR + 4]; // 23,312 B (+4 dw pad for q=3 tail reads)
    __shared__ __align__(16) float lsed[WROWS];             //    832 B (log2-domain lse)
    __shared__ __align__(16) float dbs_l[WROWS];            //    832 B (delay_b * log2e; -inf pad)

    const int tid  = threadIdx.x;
    const int wid  = tid >> 6;
    const int lane = tid & 63;
    const int q    = lane >> 4;     // quad 0..3
    const int n    = lane & 15;     // col-lane 0..15
    const int b    = blockIdx.x;
    const float* xb = x + (size_t)b * (S_ * C_);
    const unsigned* Whi = ws;
    const unsigned* Wlo = ws + WFRAG;
    const float* A2g = (const float*)(ws + 2 * WFRAG);
    const float* A4g = (const float*)(ws + 2 * WFRAG + 64);
    const float* A8g = (const float*)(ws + 2 * WFRAG + 128);

    // ---- Phase 0: stage packed x rows (vectorized, cvt_pk) + delay_b into LDS ----
    for (int i = tid; i < WROWS * 7; i += 256) {
        int r = i / 7, cg = i - r * 7;        // cg: group of 4 dwords in the 28-dword row
        f32x4 v = {0.f, 0.f, 0.f, 0.f};
        if (r < S_) {
            if (cg < 6)       __builtin_memcpy(&v, &xb[r * C_ + cg * 4], 16); // c 0..23
            else              v[0] = xb[r * C_ + 24];                          // c 24 (tail)
        }
        unsigned e0, e1, e2, e3;
        pack_hl2(v[0], v[1], e0, e1);
        pack_hl2(v[2], v[3], e2, e3);
        uint4v p = {e0, e1, e2, e3};
        *(uint4v*)&X32[r * STR + cg * 4] = p;
    }
    // CRITICAL: zero the 4 tail-pad dwords. Row 207's q=3 fragment read covers
    // dwords 5824..5827; uninitialized LDS there can hold bf16-NaN patterns and
    // MFMA NaN*0 = NaN poisons lse[207] -> P -> x_del (R9 failure).
    if (tid == 0) {
        uint4v z = {0u, 0u, 0u, 0u};
        *(uint4v*)&X32[WROWS * STR] = z;
    }
    for (int i = tid; i < WROWS; i += 256)
        dbs_l[i] = (i < S_) ? delay_b[i] * 1.44269504088896340736f : -1e30f;
    __syncthreads();

    // ---- Pass 1: lse[t] (log2 domain) via MFMA. Wave owns t-strips wid, wid+4, ... ----
    for (int st = wid; st < NSTRIP; st += 4) {
        const int t = st * 16 + n;
        const uint4v* xp = (const uint4v*)&X32[t * STR + q * 8];
        Frag fa = build_frag8(xp[0], xp[1]);       // A[m=t][k=c] (k>=25: junk x W-zeros = 0)
        float rs0 = 0.f, rs1 = 0.f, rs2 = 0.f, rs3 = 0.f;
        for (int sv = 0; sv < NSTILE; ++sv) {
            Frag fb;                               // B[k=c][n=s], pre-laid-out fragments
            fb.hi = __builtin_bit_cast(bf16x8, *(const uint4v*)&Whi[(sv * 64 + lane) * 4]);
            fb.lo = __builtin_bit_cast(bf16x8, *(const uint4v*)&Wlo[(sv * 64 + lane) * 4]);
            f32x4 L = {0.f, 0.f, 0.f, 0.f};
            L = mfma_split(fa, fb, L);
            const float dbv = dbs_l[sv * 16 + n];  // = -1e30 for padded s -> exp2 = 0
            rs0 += fexp2(L[0] + dbv);
            rs1 += fexp2(L[1] + dbv);
            rs2 += fexp2(L[2] + dbv);
            rs3 += fexp2(L[3] + dbv);
        }
#pragma unroll
        for (int off = 1; off < 16; off <<= 1) {
            rs0 += __shfl_xor(rs0, off);
            rs1 += __shfl_xor(rs1, off);
            rs2 += __shfl_xor(rs2, off);
            rs3 += __shfl_xor(rs3, off);
        }
        if (n < 4) {
            float v = (n == 0) ? rs0 : (n == 1) ? rs1 : (n == 2) ? rs2 : rs3;
            lsed[st * 16 + q * 4 + n] = flog2(v);
        }
    }
    __syncthreads();

    // ---- Pass 2: x_del = P^T X via MFMA, strip pairs; P transpose fully in-register ----
    f32x4 acc[4][2];
#pragma unroll
    for (int i = 0; i < 4; ++i)
#pragma unroll
        for (int j = 0; j < 2; ++j) acc[i][j] = f32x4{0.f, 0.f, 0.f, 0.f};

    for (int pair = 0; pair < NPAIR; ++pair) {
        const int sA = 2 * pair, sB = sA + 1;
        const bool bval = (sB < NSTRIP);
        const uint4v* xpA = (const uint4v*)&X32[(sA * 16 + n) * STR + q * 8];
        Frag faA = build_frag8(xpA[0], xpA[1]);
        Frag faB;
        if (bval) {
            const uint4v* xpB = (const uint4v*)&X32[(sB * 16 + n) * STR + q * 8];
            faB = build_frag8(xpB[0], xpB[1]);
        }
        f32x4 lseA = *(const f32x4*)&lsed[sA * 16 + q * 4];
        f32x4 lseB = bval ? *(const f32x4*)&lsed[sB * 16 + q * 4] : f32x4{0,0,0,0};
        // B2 frags (hi only): B[k=t][n=c], t = pair*32 + q*8 + j
        bf16x8 b2h[2];
        if (pair < 6) build_b2h<false>(X32, pair, q, n, b2h);
        else          build_b2h<true >(X32, pair, q, n, b2h);

#pragma unroll
        for (int si = 0; si < 4; ++si) {
            const int sv = wid + 4 * si;
            if (sv >= NSTILE) continue;          // wave-uniform branch
            Frag fb;
            fb.hi = __builtin_bit_cast(bf16x8, *(const uint4v*)&Whi[(sv * 64 + lane) * 4]);
            fb.lo = __builtin_bit_cast(bf16x8, *(const uint4v*)&Wlo[(sv * 64 + lane) * 4]);
            const float dbv = dbs_l[sv * 16 + n];
            // strip A logits -> P (hi/lo packed pairs, C-layout)
            unsigned pA0, pA1, qA0, qA1;
            {
                f32x4 L = {0.f, 0.f, 0.f, 0.f};
                L = mfma_split(faA, fb, L);
                float e0 = fexp2(L[0] + dbv - lseA[0]);
                float e1 = fexp2(L[1] + dbv - lseA[1]);
                float e2 = fexp2(L[2] + dbv - lseA[2]);
                float e3 = fexp2(L[3] + dbv - lseA[3]);
                pA0 = cvt_pk_bf16(e0, e1);
                pA1 = cvt_pk_bf16(e2, e3);
                qA0 = cvt_pk_bf16(e0 - lo16f(pA0), e1 - hi16f(pA0));
                qA1 = cvt_pk_bf16(e2 - lo16f(pA1), e3 - hi16f(pA1));
            }
            // strip B (or zeros)
            unsigned pB0 = 0u, pB1 = 0u, qB0 = 0u, qB1 = 0u;
            if (bval) {
                f32x4 L = {0.f, 0.f, 0.f, 0.f};
                L = mfma_split(faB, fb, L);
                float e0 = fexp2(L[0] + dbv - lseB[0]);
                float e1 = fexp2(L[1] + dbv - lseB[1]);
                float e2 = fexp2(L[2] + dbv - lseB[2]);
                float e3 = fexp2(L[3] + dbv - lseB[3]);
                pB0 = cvt_pk_bf16(e0, e1);
                pB1 = cvt_pk_bf16(e2, e3);
                qB0 = cvt_pk_bf16(e0 - lo16f(pB0), e1 - hi16f(pB0));
                qB1 = cvt_pk_bf16(e2 - lo16f(pB1), e3 - hi16f(pB1));
            }
            // in-register transpose to A-layout: A[m=s][k=t], k = q*8 + j
            xpose_quads(pA0, pA1, pB0, pB1);
            xpose_quads(qA0, qA1, qB0, qB1);
            uint4v hv = {pA0, pA1, pB0, pB1};
            uint4v lv = {qA0, qA1, qB0, qB1};
            bf16x8 a2h = __builtin_bit_cast(bf16x8, hv);
            bf16x8 a2l = __builtin_bit_cast(bf16x8, lv);
#pragma unroll
            for (int ct = 0; ct < 2; ++ct) {
                f32x4 c4 = acc[si][ct];
                c4 = mfma16(a2h, b2h[ct], c4);
                c4 = mfma16(a2l, b2h[ct], c4);
                acc[si][ct] = c4;
            }
        }
    }
    __syncthreads();   // all X32 reads done; safe to alias

    // ---- store x_del into reused LDS (float, stride XDS=28, 16B-aligned rows) ----
    float* fbse = (float*)&X32[0];
    float* xdelf = fbse;            // x_del: [0 .. 5600)
    float* pbuf  = fbse;            // R0 [0..1600): p_s, later p4
    float* r1    = fbse + 1600;     // R1 [1600..3200): p1, later h
    float* r2    = fbse + 3200;     // R2 [3200..4800): p2
#pragma unroll
    for (int si = 0; si < 4; ++si) {
        const int sv = wid + 4 * si;
        if (sv >= NSTILE) continue;
#pragma unroll
        for (int ct = 0; ct < 2; ++ct) {
            const int c = ct * 16 + n;
            if (c < C_) {
#pragma unroll
                for (int r = 0; r < 4; ++r) {
                    const int s = sv * 16 + q * 4 + r;
                    if (s < S_) xdelf[s * XDS + c] = acc[si][ct][r];
                }
            }
        }
    }
    __syncthreads();

    // ---- u / bgate epilogue: load row into regs, barrier, then write p into R0 ----
    {
        float a[24], a24 = 0.f;
        const bool act = tid < S_;
        if (act) {
            const f32x4* ar = (const f32x4*)&xdelf[tid * XDS];
#pragma unroll
            for (int k = 0; k < 6; ++k) *(f32x4*)&a[k * 4] = ar[k];
            a24 = xdelf[tid * XDS + 24];
        }
        __syncthreads();              // all x_del rows consumed; R0 write is safe
        if (act) {
            const int s = tid;
#pragma unroll
            for (int h = 0; h < H_; ++h) {
                float uu = fmaf(a24, U_W[h * C_ + 24], U_b[h]);
                float bb = fmaf(a24, B_W[h * C_ + 24], B_b[h]);
#pragma unroll
                for (int i = 0; i < 24; ++i) {
                    uu = fmaf(a[i], U_W[h * C_ + i], uu);
                    bb = fmaf(a[i], B_W[h * C_ + i], bb);
                }
                float sg_ = 1.0f / (1.0f + __expf(-bb));
                pbuf[s * H_ + h] = uu * sg_;
            }
        }
    }
    __syncthreads();

    // ---- linear recurrence h_s = A h_{s-1} + p_s via 8-step parallel prefix ----
    // p1 = A p[s-1] + p[s]   R0 -> R1
    for (int i2 = tid; i2 < S_ * H_; i2 += 256) {
        const int s = i2 >> 3, i = i2 & 7;
        float v = pbuf[i2];
        if (s > 0) {
            const float* pm = &pbuf[(s - 1) * H_];
#pragma unroll
            for (int j = 0; j < H_; ++j) v = fmaf(A_W[i * H_ + j], pm[j], v);
        }
        r1[i2] = v;
    }
    __syncthreads();
    // p2 = A^2 p1[s-2] + p1[s]   R1 -> R2
    for (int i2 = tid; i2 < S_ * H_; i2 += 256) {
        const int s = i2 >> 3, i = i2 & 7;
        float v = r1[i2];
        if (s > 1) {
            const float* pm = &r1[(s - 2) * H_];
#pragma unroll
            for (int j = 0; j < H_; ++j) v = fmaf(A2g[i * H_ + j], pm[j], v);
        }
        r2[i2] = v;
    }
    __syncthreads();
    // p4 = A^4 p2[s-4] + p2[s]   R2 -> R0
    for (int i2 = tid; i2 < S_ * H_; i2 += 256) {
        const int s = i2 >> 3, i = i2 & 7;
        float v = r2[i2];
        if (s > 3) {
            const float* pm = &r2[(s - 4) * H_];
#pragma unroll
            for (int j = 0; j < H_; ++j) v = fmaf(A4g[i * H_ + j], pm[j], v);
        }
        pbuf[i2] = v;
    }
    __syncthreads();
    // 8 independent chains (s mod 8) of 25 steps; 64 lanes of wave 0; h -> R1
    if (tid < 64) {
        const int r = tid >> 3, i = tid & 7;
        float A8r[H_];
#pragma unroll
        for (int j = 0; j < H_; ++j) A8r[j] = A8g[i * H_ + j];
        float h = 0.f;
        for (int k = 0; k < 25; ++k) {
            const int s = 8 * k + r;
            float v = pbuf[s * H_ + i];
#pragma unroll
            for (int j = 0; j < H_; ++j) v = fmaf(A8r[j], __shfl(h, j, 8), v);
            h = v;
            r1[s * H_ + i] = h;
        }
    }
    __syncthreads();

    // ---- out[b,s,c] = hs[s]·out_W[c,:] + out_b[c] (vectorized loads, h in R1) ----
    float* ob_ptr = out + (size_t)b * (S_ * C_);
    for (int i = tid; i < S_ * C_; i += 256) {
        int s = i / C_, c = i - s * C_;
        const f32x4* pr = (const f32x4*)&r1[s * H_];
        const f32x4* wr = (const f32x4*)&out_W[c * H_];
        f32x4 h0 = pr[0], h1 = pr[1];
        f32x4 w0 = wr[0], w1 = wr[1];
        float v = out_b[c];
        v = fmaf(h0[0], w0[0], v);
        v = fmaf(h0[1], w0[1], v);
        v = fmaf(h0[2], w0[2], v);
        v = fmaf(h0[3], w0[3], v);
        v = fmaf(h1[0], w1[0], v);
        v = fmaf(h1[1], w1[1], v);
        v = fmaf(h1[2], w1[2], v);
        v = fmaf(h1[3], w1[3], v);
        ob_ptr[i] = v;
    }
}

extern "C" void kernel_launch(void* const* d_in, const int* in_sizes, int n_in,
                              void* d_out, int out_size, void* d_ws, size_t ws_size,
                              hipStream_t stream) {
    const float* x       = (const float*)d_in[0];
    const float* delay_W = (const float*)d_in[1];
    const float* delay_b = (const float*)d_in[2];
    const float* U_W     = (const float*)d_in[3];
    const float* U_b     = (const float*)d_in[4];
    const float* A_W     = (const float*)d_in[5];
    const float* B_W     = (const float*)d_in[6];
    const float* B_b     = (const float*)d_in[7];
    const float* out_W   = (const float*)d_in[8];
    const float* out_b   = (const float*)d_in[9];
    float* out = (float*)d_out;
    unsigned* ws = (unsigned*)d_ws;   // (2*3328 + 192) dwords = 27,392 B

    prep_w_kernel<<<4, 256, 0, stream>>>(delay_W, A_W, ws);
    ssm_syn_delay_kernel<<<NB, 256, 0, stream>>>(
        x, ws, delay_b, U_W, U_b, A_W, B_W, B_b, out_W, out_b, out);
}

// Round 12
// 228.483 us; speedup vs baseline: 1.2551x; 1.0115x over previous
//
#include <hip/hip_runtime.h>

#define NB 2048
#define S_ 200
#define C_ 25
#define H_ 8
#define WROWS 208        // padded row count for packed X rows
#define STR 28           // dword stride of packed rows (b128-aligned)
#define NSTRIP 13        // ceil(200/16) t-strips
#define NSTILE 13        // ceil(200/16) s-tiles
#define NPAIR 7          // ceil(13/2) strip pairs (K=32 each)
#define XDS 28           // x_del float stride in reused LDS (= STR)
#define WFRAG (13 * 64 * 4)   // 3328 dwords per W fragment plane
#define B2N (NPAIR * 2 * 64 * 4)  // 3584 dwords: pre-built B2 fragment plane

typedef __bf16   bf16x8 __attribute__((ext_vector_type(8)));
typedef float    f32x4  __attribute__((ext_vector_type(4)));
typedef unsigned uint4v __attribute__((ext_vector_type(4)));

struct Frag { bf16x8 hi, lo; };

__device__ __forceinline__ unsigned short f2bf(float f) {
    unsigned u = __builtin_bit_cast(unsigned, f);
    return (unsigned short)((u + 0x7FFFu + ((u >> 16) & 1u)) >> 16);
}
__device__ __forceinline__ float bfh2f(unsigned short h) {
    return __builtin_bit_cast(float, (unsigned)h << 16);
}
__device__ __forceinline__ unsigned hi_pair(unsigned d0, unsigned d1) {
    return (d0 & 0xFFFFu) | (d1 << 16);
}
__device__ __forceinline__ unsigned lo_pair(unsigned d0, unsigned d1) {
    return (d0 >> 16) | (d1 & 0xFFFF0000u);
}
__device__ __forceinline__ Frag build_frag8(uint4v d0, uint4v d1) {
    uint4v h, l;
    h.x = hi_pair(d0.x, d0.y); h.y = hi_pair(d0.z, d0.w);
    h.z = hi_pair(d1.x, d1.y); h.w = hi_pair(d1.z, d1.w);
    l.x = lo_pair(d0.x, d0.y); l.y = lo_pair(d0.z, d0.w);
    l.z = lo_pair(d1.x, d1.y); l.w = lo_pair(d1.z, d1.w);
    Frag f;
    f.hi = __builtin_bit_cast(bf16x8, h);
    f.lo = __builtin_bit_cast(bf16x8, l);
    return f;
}
__device__ __forceinline__ f32x4 mfma16(bf16x8 a, bf16x8 b, f32x4 c) {
    return __builtin_amdgcn_mfma_f32_16x16x32_bf16(a, b, c, 0, 0, 0);
}
// split-precision D += A*B (drop lo*lo term)
__device__ __forceinline__ f32x4 mfma_split(const Frag& a, const Frag& b, f32x4 c) {
    c = mfma16(a.hi, b.hi, c);
    c = mfma16(a.hi, b.lo, c);
    c = mfma16(a.lo, b.hi, c);
    return c;
}
// raw transcendentals: v_exp_f32 is 2^x, v_log_f32 is log2(x)
__device__ __forceinline__ float fexp2(float x) {
    float r; asm("v_exp_f32 %0, %1" : "=v"(r) : "v"(x)); return r;
}
__device__ __forceinline__ float flog2(float x) {
    float r; asm("v_log_f32 %0, %1" : "=v"(r) : "v"(x)); return r;
}
// pack two f32 -> (bf16(lo) | bf16(hi)<<16), RNE (no builtin on gfx950)
__device__ __forceinline__ unsigned cvt_pk_bf16(float vlo, float vhi) {
    unsigned r; asm("v_cvt_pk_bf16_f32 %0, %1, %2" : "=v"(r) : "v"(vlo), "v"(vhi)); return r;
}
__device__ __forceinline__ float lo16f(unsigned p) { return __builtin_bit_cast(float, p << 16); }
__device__ __forceinline__ float hi16f(unsigned p) { return __builtin_bit_cast(float, p & 0xFFFF0000u); }
// pack two f32 into two per-value (hi|lo<<16) dwords via cvt_pk
__device__ __forceinline__ void pack_hl2(float v0, float v1, unsigned& d0, unsigned& d1) {
    unsigned hp = cvt_pk_bf16(v0, v1);
    float r0 = v0 - lo16f(hp);
    float r1 = v1 - hi16f(hp);
    unsigned lp = cvt_pk_bf16(r0, r1);
    d0 = (hp & 0xFFFFu) | (lp << 16);
    d1 = (hp >> 16) | (lp & 0xFFFF0000u);
}

// In-register MFMA C-layout (rows on quads/regs) -> A-layout (k on quads) transpose.
__device__ __forceinline__ void xpose_quads(unsigned& a0, unsigned& a1,
                                            unsigned& b0, unsigned& b1) {
    asm("v_permlane32_swap_b32 %0, %1" : "+v"(a0), "+v"(b0));
    asm("v_permlane32_swap_b32 %0, %1" : "+v"(a1), "+v"(b1));
    asm("v_permlane16_swap_b32 %0, %1" : "+v"(a0), "+v"(b0));
    asm("v_permlane16_swap_b32 %0, %1" : "+v"(a1), "+v"(b1));
}

// ---------- prep kernel: W fragment planes (pre-scaled by log2e) + A^2, A^4, A^8 ----------
__global__ void prep_w_kernel(const float* __restrict__ delay_W,
                              const float* __restrict__ A_W,
                              unsigned* __restrict__ ws) {
    const float LOG2E = 1.44269504088896340736f;
    unsigned* Whi = ws;
    unsigned* Wlo = ws + WFRAG;
    for (int idx = blockIdx.x * 256 + threadIdx.x; idx < WFRAG; idx += gridDim.x * 256) {
        int d = idx & 3, lane = (idx >> 2) & 63, sv = idx >> 8;
        int q = lane >> 4, nn = lane & 15;
        int s  = sv * 16 + nn;
        int c0 = q * 8 + 2 * d;
        float v0 = (s < S_ && c0     < C_) ? delay_W[s * C_ + c0]     * LOG2E : 0.f;
        float v1 = (s < S_ && c0 + 1 < C_) ? delay_W[s * C_ + c0 + 1] * LOG2E : 0.f;
        unsigned short h0 = f2bf(v0), h1 = f2bf(v1);
        unsigned short l0 = f2bf(v0 - bfh2f(h0)), l1 = f2bf(v1 - bfh2f(h1));
        Whi[idx] = (unsigned)h0 | ((unsigned)h1 << 16);
        Wlo[idx] = (unsigned)l0 | ((unsigned)l1 << 16);
    }
    // A^2, A^4, A^8 for the 8-step parallel recurrence
    __shared__ float A2s[64];
    __shared__ float A4s[64];
    if (blockIdx.x == 0) {
        float* A2g = (float*)(ws + 2 * WFRAG);
        float* A4g = (float*)(ws + 2 * WFRAG + 64);
        float* A8g = (float*)(ws + 2 * WFRAG + 128);
        const int i = threadIdx.x >> 3, j = threadIdx.x & 7;
        if (threadIdx.x < 64) {
            float s = 0.f;
            for (int k = 0; k < 8; ++k) s = fmaf(A_W[i * 8 + k], A_W[k * 8 + j], s);
            A2s[threadIdx.x] = s; A2g[threadIdx.x] = s;
        }
        __syncthreads();
        if (threadIdx.x < 64) {
            float s = 0.f;
            for (int k = 0; k < 8; ++k) s = fmaf(A2s[i * 8 + k], A2s[k * 8 + j], s);
            A4s[threadIdx.x] = s; A4g[threadIdx.x] = s;
        }
        __syncthreads();
        if (threadIdx.x < 64) {
            float s = 0.f;
            for (int k = 0; k < 8; ++k) s = fmaf(A4s[i * 8 + k], A4s[k * 8 + j], s);
            A8g[threadIdx.x] = s;
        }
    }
}

// ---------- main kernel: one block per batch ----------
// 39,312 B LDS -> 4 blocks/CU (occupancy-flat region per R5 vs R11);
// launch_bounds(256,4) -> 128-reg allocator budget (no spill headroom issue).
__global__ __launch_bounds__(256, 4) void ssm_syn_delay_kernel(
    const float* __restrict__ x,       const unsigned* __restrict__ ws,
    const float* __restrict__ delay_b, const float* __restrict__ U_W,
    const float* __restrict__ U_b,     const float* __restrict__ A_W,
    const float* __restrict__ B_W,     const float* __restrict__ B_b,
    const float* __restrict__ out_W,   const float* __restrict__ out_b,
    float* __restrict__ out)
{
    __shared__ __align__(16) unsigned X32[WROWS * STR + 4]; // 23,312 B (+4 dw pad for q=3 tail reads)
    __shared__ __align__(16) unsigned B2T[B2N];             // 14,336 B: prebuilt B2 frags (hi bf16)
    __shared__ __align__(16) float lsed[WROWS];             //    832 B (log2-domain lse)
    __shared__ __align__(16) float dbs_l[WROWS];            //    832 B (delay_b * log2e; -inf pad)

    const int tid  = threadIdx.x;
    const int wid  = tid >> 6;
    const int lane = tid & 63;
    const int q    = lane >> 4;     // quad 0..3
    const int n    = lane & 15;     // col-lane 0..15
    const int b    = blockIdx.x;
    const float* xb = x + (size_t)b * (S_ * C_);
    const unsigned* Whi = ws;
    const unsigned* Wlo = ws + WFRAG;
    const float* A2g = (const float*)(ws + 2 * WFRAG);
    const float* A4g = (const float*)(ws + 2 * WFRAG + 64);
    const float* A8g = (const float*)(ws + 2 * WFRAG + 128);

    // ---- Phase 0: stage packed x rows (vectorized, cvt_pk) + delay_b into LDS ----
    for (int i = tid; i < WROWS * 7; i += 256) {
        int r = i / 7, cg = i - r * 7;        // cg: group of 4 dwords in the 28-dword row
        f32x4 v = {0.f, 0.f, 0.f, 0.f};
        if (r < S_) {
            if (cg < 6)       __builtin_memcpy(&v, &xb[r * C_ + cg * 4], 16); // c 0..23
            else              v[0] = xb[r * C_ + 24];                          // c 24 (tail)
        }
        unsigned e0, e1, e2, e3;
        pack_hl2(v[0], v[1], e0, e1);
        pack_hl2(v[2], v[3], e2, e3);
        uint4v p = {e0, e1, e2, e3};
        *(uint4v*)&X32[r * STR + cg * 4] = p;
    }
    // Zero the 4 tail-pad dwords (row 207 q=3 reads them; NaN*0=NaN — R9 lesson).
    if (tid == 0) {
        uint4v z = {0u, 0u, 0u, 0u};
        *(uint4v*)&X32[WROWS * STR] = z;
    }
    for (int i = tid; i < WROWS; i += 256)
        dbs_l[i] = (i < S_) ? delay_b[i] * 1.44269504088896340736f : -1e30f;
    __syncthreads();

    // ---- Stage B2 fragment plane: B2T[((pair*2+ct)*64+lane)*4 + k] packs
    //      bf16(X[t0,c]) | bf16(X[t0+1,c])<<16 with t0 = pair*32 + q*8 + 2k,
    //      c = ct*16 + n. One-time; replaces per-pair per-wave column gathers.
    for (int idx = tid; idx < B2N; idx += 256) {
        const int k  = idx & 3;
        const int ln = (idx >> 2) & 63;
        const int ct = (idx >> 8) & 1;
        const int pr = idx >> 9;
        const int t0 = pr * 32 + (ln >> 4) * 8 + 2 * k;
        const int c  = ct * 16 + (ln & 15);
        unsigned u0 = (t0     < WROWS) ? X32[t0 * STR + c] : 0u;
        unsigned u1 = (t0 + 1 < WROWS) ? X32[(t0 + 1) * STR + c] : 0u;
        B2T[idx] = hi_pair(u0, u1);
    }
    // (pass-1 barrier below publishes B2T for pass 2)

    // ---- Pass 1: lse[t] (log2 domain), sv-outer; fa[4]+rs[4] resident ----
    {
        Frag fa[4];
        f32x4 rs[4];
#pragma unroll
        for (int k2 = 0; k2 < 4; ++k2) {
            rs[k2] = f32x4{0.f, 0.f, 0.f, 0.f};
            const int st = wid + 4 * k2;
            if (st < NSTRIP) {
                const uint4v* xp = (const uint4v*)&X32[(st * 16 + n) * STR + q * 8];
                fa[k2] = build_frag8(xp[0], xp[1]);   // A[m=t][k=c] (k>=25 junk x W-zeros)
            }
        }
        for (int sv = 0; sv < NSTILE; ++sv) {
            Frag fb;                                  // B[k=c][n=s], pre-laid-out fragments
            fb.hi = __builtin_bit_cast(bf16x8, *(const uint4v*)&Whi[(sv * 64 + lane) * 4]);
            fb.lo = __builtin_bit_cast(bf16x8, *(const uint4v*)&Wlo[(sv * 64 + lane) * 4]);
            const float dbv = dbs_l[sv * 16 + n];     // = -1e30 for padded s -> exp2 = 0
#pragma unroll
            for (int k2 = 0; k2 < 4; ++k2) {
                if (wid + 4 * k2 >= NSTRIP) continue; // wave-uniform
                f32x4 L = {0.f, 0.f, 0.f, 0.f};
                L = mfma_split(fa[k2], fb, L);
                rs[k2][0] += fexp2(L[0] + dbv);
                rs[k2][1] += fexp2(L[1] + dbv);
                rs[k2][2] += fexp2(L[2] + dbv);
                rs[k2][3] += fexp2(L[3] + dbv);
            }
        }
#pragma unroll
        for (int k2 = 0; k2 < 4; ++k2) {
            const int st = wid + 4 * k2;
            if (st >= NSTRIP) continue;
            float r0 = rs[k2][0], r1 = rs[k2][1], r2 = rs[k2][2], r3 = rs[k2][3];
#pragma unroll
            for (int off = 1; off < 16; off <<= 1) {
                r0 += __shfl_xor(r0, off);
                r1 += __shfl_xor(r1, off);
                r2 += __shfl_xor(r2, off);
                r3 += __shfl_xor(r3, off);
            }
            if (n < 4) {
                float v = (n == 0) ? r0 : (n == 1) ? r1 : (n == 2) ? r2 : r3;
                lsed[st * 16 + q * 4 + n] = flog2(v);
            }
        }
    }
    __syncthreads();

    // ---- Pass 2: x_del = P^T X via MFMA, strip pairs; P transpose fully in-register ----
    f32x4 acc[4][2];
#pragma unroll
    for (int i = 0; i < 4; ++i)
#pragma unroll
        for (int j = 0; j < 2; ++j) acc[i][j] = f32x4{0.f, 0.f, 0.f, 0.f};

    for (int pair = 0; pair < NPAIR; ++pair) {
        const int sA = 2 * pair, sB = sA + 1;
        const bool bval = (sB < NSTRIP);
        const uint4v* xpA = (const uint4v*)&X32[(sA * 16 + n) * STR + q * 8];
        Frag faA = build_frag8(xpA[0], xpA[1]);
        Frag faB;
        if (bval) {
            const uint4v* xpB = (const uint4v*)&X32[(sB * 16 + n) * STR + q * 8];
            faB = build_frag8(xpB[0], xpB[1]);
        }
        f32x4 lseA = *(const f32x4*)&lsed[sA * 16 + q * 4];
        f32x4 lseB = bval ? *(const f32x4*)&lsed[sB * 16 + q * 4] : f32x4{0,0,0,0};
        // B2 frags (hi only): direct b128 loads from prebuilt plane, no gather/pack
        bf16x8 b2h[2];
#pragma unroll
        for (int ct = 0; ct < 2; ++ct)
            b2h[ct] = __builtin_bit_cast(bf16x8,
                        *(const uint4v*)&B2T[((pair * 2 + ct) * 64 + lane) * 4]);

#pragma unroll
        for (int si = 0; si < 4; ++si) {
            const int sv = wid + 4 * si;
            if (sv >= NSTILE) continue;          // wave-uniform branch
            Frag fb;
            fb.hi = __builtin_bit_cast(bf16x8, *(const uint4v*)&Whi[(sv * 64 + lane) * 4]);
            fb.lo = __builtin_bit_cast(bf16x8, *(const uint4v*)&Wlo[(sv * 64 + lane) * 4]);
            const float dbv = dbs_l[sv * 16 + n];
            // strip A logits -> P (hi/lo packed pairs, C-layout)
            unsigned pA0, pA1, qA0, qA1;
            {
                f32x4 L = {0.f, 0.f, 0.f, 0.f};
                L = mfma_split(faA, fb, L);
                float e0 = fexp2(L[0] + dbv - lseA[0]);
                float e1 = fexp2(L[1] + dbv - lseA[1]);
                float e2 = fexp2(L[2] + dbv - lseA[2]);
                float e3 = fexp2(L[3] + dbv - lseA[3]);
                pA0 = cvt_pk_bf16(e0, e1);
                pA1 = cvt_pk_bf16(e2, e3);
                qA0 = cvt_pk_bf16(e0 - lo16f(pA0), e1 - hi16f(pA0));
                qA1 = cvt_pk_bf16(e2 - lo16f(pA1), e3 - hi16f(pA1));
            }
            // strip B (or zeros)
            unsigned pB0 = 0u, pB1 = 0u, qB0 = 0u, qB1 = 0u;
            if (bval) {
                f32x4 L = {0.f, 0.f, 0.f, 0.f};
                L = mfma_split(faB, fb, L);
                float e0 = fexp2(L[0] + dbv - lseB[0]);
                float e1 = fexp2(L[1] + dbv - lseB[1]);
                float e2 = fexp2(L[2] + dbv - lseB[2]);
                float e3 = fexp2(L[3] + dbv - lseB[3]);
                pB0 = cvt_pk_bf16(e0, e1);
                pB1 = cvt_pk_bf16(e2, e3);
                qB0 = cvt_pk_bf16(e0 - lo16f(pB0), e1 - hi16f(pB0));
                qB1 = cvt_pk_bf16(e2 - lo16f(pB1), e3 - hi16f(pB1));
            }
            // in-register transpose to A-layout: A[m=s][k=t], k = q*8 + j
            xpose_quads(pA0, pA1, pB0, pB1);
            xpose_quads(qA0, qA1, qB0, qB1);
            uint4v hv = {pA0, pA1, pB0, pB1};
            uint4v lv = {qA0, qA1, qB0, qB1};
            bf16x8 a2h = __builtin_bit_cast(bf16x8, hv);
            bf16x8 a2l = __builtin_bit_cast(bf16x8, lv);
#pragma unroll
            for (int ct = 0; ct < 2; ++ct) {
                f32x4 c4 = acc[si][ct];
                c4 = mfma16(a2h, b2h[ct], c4);
                c4 = mfma16(a2l, b2h[ct], c4);
                acc[si][ct] = c4;
            }
        }
    }
    __syncthreads();   // all X32 reads done; safe to alias

    // ---- store x_del into reused LDS (float, stride XDS=28, 16B-aligned rows) ----
    float* fbse = (float*)&X32[0];
    float* xdelf = fbse;            // x_del: [0 .. 5600)
    float* pbuf  = fbse;            // R0 [0..1600): p_s, later p4
    float* r1    = fbse + 1600;     // R1 [1600..3200): p1, later h
    float* r2    = fbse + 3200;     // R2 [3200..4800): p2
#pragma unroll
    for (int si = 0; si < 4; ++si) {
        const int sv = wid + 4 * si;
        if (sv >= NSTILE) continue;
#pragma unroll
        for (int ct = 0; ct < 2; ++ct) {
            const int c = ct * 16 + n;
            if (c < C_) {
#pragma unroll
                for (int r = 0; r < 4; ++r) {
                    const int s = sv * 16 + q * 4 + r;
                    if (s < S_) xdelf[s * XDS + c] = acc[si][ct][r];
                }
            }
        }
    }
    __syncthreads();

    // ---- u / bgate epilogue: load row into regs, barrier, then write p into R0 ----
    {
        float a[24], a24 = 0.f;
        const bool act = tid < S_;
        if (act) {
            const f32x4* ar = (const f32x4*)&xdelf[tid * XDS];
#pragma unroll
            for (int k = 0; k < 6; ++k) *(f32x4*)&a[k * 4] = ar[k];
            a24 = xdelf[tid * XDS + 24];
        }
        __syncthreads();              // all x_del rows consumed; R0 write is safe
        if (act) {
            const int s = tid;
#pragma unroll
            for (int h = 0; h < H_; ++h) {
                float uu = fmaf(a24, U_W[h * C_ + 24], U_b[h]);
                float bb = fmaf(a24, B_W[h * C_ + 24], B_b[h]);
#pragma unroll
                for (int i = 0; i < 24; ++i) {
                    uu = fmaf(a[i], U_W[h * C_ + i], uu);
                    bb = fmaf(a[i], B_W[h * C_ + i], bb);
                }
                float sg_ = 1.0f / (1.0f + __expf(-bb));
                pbuf[s * H_ + h] = uu * sg_;
            }
        }
    }
    __syncthreads();

    // ---- linear recurrence h_s = A h_{s-1} + p_s via 8-step parallel prefix ----
    // p1 = A p[s-1] + p[s]   R0 -> R1
    for (int i2 = tid; i2 < S_ * H_; i2 += 256) {
        const int s = i2 >> 3, i = i2 & 7;
        float v = pbuf[i2];
        if (s > 0) {
            const float* pm = &pbuf[(s - 1) * H_];
#pragma unroll
            for (int j = 0; j < H_; ++j) v = fmaf(A_W[i * H_ + j], pm[j], v);
        }
        r1[i2] = v;
    }
    __syncthreads();
    // p2 = A^2 p1[s-2] + p1[s]   R1 -> R2
    for (int i2 = tid; i2 < S_ * H_; i2 += 256) {
        const int s = i2 >> 3, i = i2 & 7;
        float v = r1[i2];
        if (s > 1) {
            const float* pm = &r1[(s - 2) * H_];
#pragma unroll
            for (int j = 0; j < H_; ++j) v = fmaf(A2g[i * H_ + j], pm[j], v);
        }
        r2[i2] = v;
    }
    __syncthreads();
    // p4 = A^4 p2[s-4] + p2[s]   R2 -> R0
    for (int i2 = tid; i2 < S_ * H_; i2 += 256) {
        const int s = i2 >> 3, i = i2 & 7;
        float v = r2[i2];
        if (s > 3) {
            const float* pm = &r2[(s - 4) * H_];
#pragma unroll
            for (int j = 0; j < H_; ++j) v = fmaf(A4g[i * H_ + j], pm[j], v);
        }
        pbuf[i2] = v;
    }
    __syncthreads();
    // 8 independent chains (s mod 8) of 25 steps; 64 lanes of wave 0; h -> R1
    if (tid < 64) {
        const int r = tid >> 3, i = tid & 7;
        float A8r[H_];
#pragma unroll
        for (int j = 0; j < H_; ++j) A8r[j] = A8g[i * H_ + j];
        float h = 0.f;
        for (int k = 0; k < 25; ++k) {
            const int s = 8 * k + r;
            float v = pbuf[s * H_ + i];
#pragma unroll
            for (int j = 0; j < H_; ++j) v = fmaf(A8r[j], __shfl(h, j, 8), v);
            h = v;
            r1[s * H_ + i] = h;
        }
    }
    __syncthreads();

    // ---- out[b,s,c] = hs[s]·out_W[c,:] + out_b[c] (vectorized loads, h in R1) ----
    float* ob_ptr = out + (size_t)b * (S_ * C_);
    for (int i = tid; i < S_ * C_; i += 256) {
        int s = i / C_, c = i - s * C_;
        const f32x4* pr = (const f32x4*)&r1[s * H_];
        const f32x4* wr = (const f32x4*)&out_W[c * H_];
        f32x4 h0 = pr[0], h1 = pr[1];
        f32x4 w0 = wr[0], w1 = wr[1];
        float v = out_b[c];
        v = fmaf(h0[0], w0[0], v);
        v = fmaf(h0[1], w0[1], v);
        v = fmaf(h0[2], w0[2], v);
        v = fmaf(h0[3], w0[3], v);
        v = fmaf(h1[0], w1[0], v);
        v = fmaf(h1[1], w1[1], v);
        v = fmaf(h1[2], w1[2], v);
        v = fmaf(h1[3], w1[3], v);
        ob_ptr[i] = v;
    }
}

extern "C" void kernel_launch(void* const* d_in, const int* in_sizes, int n_in,
                              void* d_out, int out_size, void* d_ws, size_t ws_size,
                              hipStream_t stream) {
    const float* x       = (const float*)d_in[0];
    const float* delay_W = (const float*)d_in[1];
    const float* delay_b = (const float*)d_in[2];
    const float* U_W     = (const float*)d_in[3];
    const float* U_b     = (const float*)d_in[4];
    const float* A_W     = (const float*)d_in[5];
    const float* B_W     = (const float*)d_in[6];
    const float* B_b     = (const float*)d_in[7];
    const float* out_W   = (const float*)d_in[8];
    const float* out_b   = (const float*)d_in[9];
    float* out = (float*)d_out;
    unsigned* ws = (unsigned*)d_ws;   // (2*3328 + 192) dwords = 27,392 B

    prep_w_kernel<<<4, 256, 0, stream>>>(delay_W, A_W, ws);
    ssm_syn_delay_kernel<<<NB, 256, 0, stream>>>(
        x, ws, delay_b, U_W, U_b, A_W, B_W, B_b, out_W, out_b, out);
}

// Round 14
// 221.941 us; speedup vs baseline: 1.2921x; 1.0295x over previous
//
#include <hip/hip_runtime.h>

#define NB 2048
#define S_ 200
#define C_ 25
#define H_ 8
#define WROWS 208        // padded row count for packed X rows
#define STR 28           // dword stride of packed rows (b128-aligned)
#define NSTRIP 13        // ceil(200/16) t-strips
#define NSTILE 13        // ceil(200/16) s-tiles
#define NPAIR 7          // ceil(13/2) strip pairs (K=32 each)
#define XDS 28           // x_del float stride in reused LDS (= STR)
#define WFRAG (13 * 64 * 4)   // 3328 dwords per W fragment plane
#define B2N (NPAIR * 2 * 64 * 4)  // 3584 dwords: pre-built B2 fragment plane

typedef __bf16   bf16x8 __attribute__((ext_vector_type(8)));
typedef float    f32x4  __attribute__((ext_vector_type(4)));
typedef unsigned uint4v __attribute__((ext_vector_type(4)));

struct Frag { bf16x8 hi, lo; };

__device__ __forceinline__ unsigned short f2bf(float f) {
    unsigned u = __builtin_bit_cast(unsigned, f);
    return (unsigned short)((u + 0x7FFFu + ((u >> 16) & 1u)) >> 16);
}
__device__ __forceinline__ float bfh2f(unsigned short h) {
    return __builtin_bit_cast(float, (unsigned)h << 16);
}
__device__ __forceinline__ unsigned hi_pair(unsigned d0, unsigned d1) {
    return (d0 & 0xFFFFu) | (d1 << 16);
}
__device__ __forceinline__ unsigned lo_pair(unsigned d0, unsigned d1) {
    return (d0 >> 16) | (d1 & 0xFFFF0000u);
}
__device__ __forceinline__ Frag build_frag8(uint4v d0, uint4v d1) {
    uint4v h, l;
    h.x = hi_pair(d0.x, d0.y); h.y = hi_pair(d0.z, d0.w);
    h.z = hi_pair(d1.x, d1.y); h.w = hi_pair(d1.z, d1.w);
    l.x = lo_pair(d0.x, d0.y); l.y = lo_pair(d0.z, d0.w);
    l.z = lo_pair(d1.x, d1.y); l.w = lo_pair(d1.z, d1.w);
    Frag f;
    f.hi = __builtin_bit_cast(bf16x8, h);
    f.lo = __builtin_bit_cast(bf16x8, l);
    return f;
}
__device__ __forceinline__ f32x4 mfma16(bf16x8 a, bf16x8 b, f32x4 c) {
    return __builtin_amdgcn_mfma_f32_16x16x32_bf16(a, b, c, 0, 0, 0);
}
// split-precision D += A*B (drop lo*lo term) — used for logits only
__device__ __forceinline__ f32x4 mfma_split(const Frag& a, const Frag& b, f32x4 c) {
    c = mfma16(a.hi, b.hi, c);
    c = mfma16(a.hi, b.lo, c);
    c = mfma16(a.lo, b.hi, c);
    return c;
}
// raw transcendentals: v_exp_f32 is 2^x, v_log_f32 is log2(x)
__device__ __forceinline__ float fexp2(float x) {
    float r; asm("v_exp_f32 %0, %1" : "=v"(r) : "v"(x)); return r;
}
__device__ __forceinline__ float flog2(float x) {
    float r; asm("v_log_f32 %0, %1" : "=v"(r) : "v"(x)); return r;
}
// pack two f32 -> (bf16(lo) | bf16(hi)<<16), RNE (no builtin on gfx950)
__device__ __forceinline__ unsigned cvt_pk_bf16(float vlo, float vhi) {
    unsigned r; asm("v_cvt_pk_bf16_f32 %0, %1, %2" : "=v"(r) : "v"(vlo), "v"(vhi)); return r;
}
__device__ __forceinline__ float lo16f(unsigned p) { return __builtin_bit_cast(float, p << 16); }
__device__ __forceinline__ float hi16f(unsigned p) { return __builtin_bit_cast(float, p & 0xFFFF0000u); }
// pack two f32 into two per-value (hi|lo<<16) dwords via cvt_pk
__device__ __forceinline__ void pack_hl2(float v0, float v1, unsigned& d0, unsigned& d1) {
    unsigned hp = cvt_pk_bf16(v0, v1);
    float r0 = v0 - lo16f(hp);
    float r1 = v1 - hi16f(hp);
    unsigned lp = cvt_pk_bf16(r0, r1);
    d0 = (hp & 0xFFFFu) | (lp << 16);
    d1 = (hp >> 16) | (lp & 0xFFFF0000u);
}

// In-register MFMA C-layout (rows on quads/regs) -> A-layout (k on quads) transpose.
__device__ __forceinline__ void xpose_quads(unsigned& a0, unsigned& a1,
                                            unsigned& b0, unsigned& b1) {
    asm("v_permlane32_swap_b32 %0, %1" : "+v"(a0), "+v"(b0));
    asm("v_permlane32_swap_b32 %0, %1" : "+v"(a1), "+v"(b1));
    asm("v_permlane16_swap_b32 %0, %1" : "+v"(a0), "+v"(b0));
    asm("v_permlane16_swap_b32 %0, %1" : "+v"(a1), "+v"(b1));
}

// ---------- prep kernel: W fragment planes (pre-scaled by log2e) + A^2, A^4, A^8 ----------
__global__ void prep_w_kernel(const float* __restrict__ delay_W,
                              const float* __restrict__ A_W,
                              unsigned* __restrict__ ws) {
    const float LOG2E = 1.44269504088896340736f;
    unsigned* Whi = ws;
    unsigned* Wlo = ws + WFRAG;
    for (int idx = blockIdx.x * 256 + threadIdx.x; idx < WFRAG; idx += gridDim.x * 256) {
        int d = idx & 3, lane = (idx >> 2) & 63, sv = idx >> 8;
        int q = lane >> 4, nn = lane & 15;
        int s  = sv * 16 + nn;
        int c0 = q * 8 + 2 * d;
        float v0 = (s < S_ && c0     < C_) ? delay_W[s * C_ + c0]     * LOG2E : 0.f;
        float v1 = (s < S_ && c0 + 1 < C_) ? delay_W[s * C_ + c0 + 1] * LOG2E : 0.f;
        unsigned short h0 = f2bf(v0), h1 = f2bf(v1);
        unsigned short l0 = f2bf(v0 - bfh2f(h0)), l1 = f2bf(v1 - bfh2f(h1));
        Whi[idx] = (unsigned)h0 | ((unsigned)h1 << 16);
        Wlo[idx] = (unsigned)l0 | ((unsigned)l1 << 16);
    }
    // A^2, A^4, A^8 for the 8-step parallel recurrence
    __shared__ float A2s[64];
    __shared__ float A4s[64];
    if (blockIdx.x == 0) {
        float* A2g = (float*)(ws + 2 * WFRAG);
        float* A4g = (float*)(ws + 2 * WFRAG + 64);
        float* A8g = (float*)(ws + 2 * WFRAG + 128);
        const int i = threadIdx.x >> 3, j = threadIdx.x & 7;
        if (threadIdx.x < 64) {
            float s = 0.f;
            for (int k = 0; k < 8; ++k) s = fmaf(A_W[i * 8 + k], A_W[k * 8 + j], s);
            A2s[threadIdx.x] = s; A2g[threadIdx.x] = s;
        }
        __syncthreads();
        if (threadIdx.x < 64) {
            float s = 0.f;
            for (int k = 0; k < 8; ++k) s = fmaf(A2s[i * 8 + k], A2s[k * 8 + j], s);
            A4s[threadIdx.x] = s; A4g[threadIdx.x] = s;
        }
        __syncthreads();
        if (threadIdx.x < 64) {
            float s = 0.f;
            for (int k = 0; k < 8; ++k) s = fmaf(A4s[i * 8 + k], A4s[k * 8 + j], s);
            A8g[threadIdx.x] = s;
        }
    }
}

// ---------- main kernel: one block per batch ----------
// 39,312 B LDS -> 4 blocks/CU; launch_bounds(256,4) -> 128-reg budget (no spill).
__global__ __launch_bounds__(256, 4) void ssm_syn_delay_kernel(
    const float* __restrict__ x,       const unsigned* __restrict__ ws,
    const float* __restrict__ delay_b, const float* __restrict__ U_W,
    const float* __restrict__ U_b,     const float* __restrict__ A_W,
    const float* __restrict__ B_W,     const float* __restrict__ B_b,
    const float* __restrict__ out_W,   const float* __restrict__ out_b,
    float* __restrict__ out)
{
    __shared__ __align__(16) unsigned X32[WROWS * STR + 4]; // 23,312 B (+4 dw pad for q=3 tail reads)
    __shared__ __align__(16) unsigned B2T[B2N];             // 14,336 B: prebuilt B2 frags (hi bf16)
    __shared__ __align__(16) float lsed[WROWS];             //    832 B (log2-domain lse)
    __shared__ __align__(16) float dbs_l[WROWS];            //    832 B (delay_b * log2e; -inf pad)

    const int tid  = threadIdx.x;
    const int wid  = tid >> 6;
    const int lane = tid & 63;
    const int q    = lane >> 4;     // quad 0..3
    const int n    = lane & 15;     // col-lane 0..15
    const int b    = blockIdx.x;
    const float* xb = x + (size_t)b * (S_ * C_);
    const unsigned* Whi = ws;
    const unsigned* Wlo = ws + WFRAG;
    const float* A2g = (const float*)(ws + 2 * WFRAG);
    const float* A4g = (const float*)(ws + 2 * WFRAG + 64);
    const float* A8g = (const float*)(ws + 2 * WFRAG + 128);

    // ---- Phase 0: stage packed x rows (vectorized, cvt_pk) + delay_b into LDS ----
    for (int i = tid; i < WROWS * 7; i += 256) {
        int r = i / 7, cg = i - r * 7;        // cg: group of 4 dwords in the 28-dword row
        f32x4 v = {0.f, 0.f, 0.f, 0.f};
        if (r < S_) {
            if (cg < 6)       __builtin_memcpy(&v, &xb[r * C_ + cg * 4], 16); // c 0..23
            else              v[0] = xb[r * C_ + 24];                          // c 24 (tail)
        }
        unsigned e0, e1, e2, e3;
        pack_hl2(v[0], v[1], e0, e1);
        pack_hl2(v[2], v[3], e2, e3);
        uint4v p = {e0, e1, e2, e3};
        *(uint4v*)&X32[r * STR + cg * 4] = p;
    }
    // Zero the 4 tail-pad dwords (row 207 q=3 reads them; NaN*0=NaN — R9 lesson).
    if (tid == 0) {
        uint4v z = {0u, 0u, 0u, 0u};
        *(uint4v*)&X32[WROWS * STR] = z;
    }
    for (int i = tid; i < WROWS; i += 256)
        dbs_l[i] = (i < S_) ? delay_b[i] * 1.44269504088896340736f : -1e30f;
    __syncthreads();

    // ---- Stage B2 fragment plane (one-time; replaces per-pair column gathers) ----
    for (int idx = tid; idx < B2N; idx += 256) {
        const int k  = idx & 3;
        const int ln = (idx >> 2) & 63;
        const int ct = (idx >> 8) & 1;
        const int pr = idx >> 9;
        const int t0 = pr * 32 + (ln >> 4) * 8 + 2 * k;
        const int c  = ct * 16 + (ln & 15);
        unsigned u0 = (t0     < WROWS) ? X32[t0 * STR + c] : 0u;
        unsigned u1 = (t0 + 1 < WROWS) ? X32[(t0 + 1) * STR + c] : 0u;
        B2T[idx] = hi_pair(u0, u1);
    }
    // (pass-1 barrier below publishes B2T for pass 2)

    // ---- Pass 1: lse[t] (log2 domain), sv-outer; fa[4]+rs[4] resident ----
    {
        Frag fa[4];
        f32x4 rs[4];
#pragma unroll
        for (int k2 = 0; k2 < 4; ++k2) {
            rs[k2] = f32x4{0.f, 0.f, 0.f, 0.f};
            const int st = wid + 4 * k2;
            if (st < NSTRIP) {
                const uint4v* xp = (const uint4v*)&X32[(st * 16 + n) * STR + q * 8];
                fa[k2] = build_frag8(xp[0], xp[1]);   // A[m=t][k=c] (k>=25 junk x W-zeros)
            }
        }
        for (int sv = 0; sv < NSTILE; ++sv) {
            Frag fb;                                  // B[k=c][n=s], pre-laid-out fragments
            fb.hi = __builtin_bit_cast(bf16x8, *(const uint4v*)&Whi[(sv * 64 + lane) * 4]);
            fb.lo = __builtin_bit_cast(bf16x8, *(const uint4v*)&Wlo[(sv * 64 + lane) * 4]);
            const float dbv = dbs_l[sv * 16 + n];     // = -1e30 for padded s -> exp2 = 0
#pragma unroll
            for (int k2 = 0; k2 < 4; ++k2) {
                if (wid + 4 * k2 >= NSTRIP) continue; // wave-uniform
                f32x4 L = {0.f, 0.f, 0.f, 0.f};
                L = mfma_split(fa[k2], fb, L);
                rs[k2][0] += fexp2(L[0] + dbv);
                rs[k2][1] += fexp2(L[1] + dbv);
                rs[k2][2] += fexp2(L[2] + dbv);
                rs[k2][3] += fexp2(L[3] + dbv);
            }
        }
#pragma unroll
        for (int k2 = 0; k2 < 4; ++k2) {
            const int st = wid + 4 * k2;
            if (st >= NSTRIP) continue;
            float r0 = rs[k2][0], r1 = rs[k2][1], r2 = rs[k2][2], r3 = rs[k2][3];
#pragma unroll
            for (int off = 1; off < 16; off <<= 1) {
                r0 += __shfl_xor(r0, off);
                r1 += __shfl_xor(r1, off);
                r2 += __shfl_xor(r2, off);
                r3 += __shfl_xor(r3, off);
            }
            if (n < 4) {
                float v = (n == 0) ? r0 : (n == 1) ? r1 : (n == 2) ? r2 : r3;
                lsed[st * 16 + q * 4 + n] = flog2(v);
            }
        }
    }
    __syncthreads();

    // ---- Pass 2: x_del = P^T X via MFMA; P hi-plane only (lo-plane dropped:
    //      output is bf16-quantization dominated — absmax pinned at 2^-9 R5-R12) ----
    f32x4 acc[4][2];
#pragma unroll
    for (int i = 0; i < 4; ++i)
#pragma unroll
        for (int j = 0; j < 2; ++j) acc[i][j] = f32x4{0.f, 0.f, 0.f, 0.f};

    for (int pair = 0; pair < NPAIR; ++pair) {
        const int sA = 2 * pair, sB = sA + 1;
        const bool bval = (sB < NSTRIP);
        const uint4v* xpA = (const uint4v*)&X32[(sA * 16 + n) * STR + q * 8];
        Frag faA = build_frag8(xpA[0], xpA[1]);
        Frag faB;
        if (bval) {
            const uint4v* xpB = (const uint4v*)&X32[(sB * 16 + n) * STR + q * 8];
            faB = build_frag8(xpB[0], xpB[1]);
        }
        f32x4 lseA = *(const f32x4*)&lsed[sA * 16 + q * 4];
        f32x4 lseB = bval ? *(const f32x4*)&lsed[sB * 16 + q * 4] : f32x4{0,0,0,0};
        // B2 frags (hi only): direct b128 loads from prebuilt plane
        bf16x8 b2h[2];
#pragma unroll
        for (int ct = 0; ct < 2; ++ct)
            b2h[ct] = __builtin_bit_cast(bf16x8,
                        *(const uint4v*)&B2T[((pair * 2 + ct) * 64 + lane) * 4]);

#pragma unroll
        for (int si = 0; si < 4; ++si) {
            const int sv = wid + 4 * si;
            if (sv >= NSTILE) continue;          // wave-uniform branch
            Frag fb;
            fb.hi = __builtin_bit_cast(bf16x8, *(const uint4v*)&Whi[(sv * 64 + lane) * 4]);
            fb.lo = __builtin_bit_cast(bf16x8, *(const uint4v*)&Wlo[(sv * 64 + lane) * 4]);
            const float dbv = dbs_l[sv * 16 + n];
            // strip A logits -> P (hi packed pairs, C-layout)
            unsigned pA0, pA1;
            {
                f32x4 L = {0.f, 0.f, 0.f, 0.f};
                L = mfma_split(faA, fb, L);
                float e0 = fexp2(L[0] + dbv - lseA[0]);
                float e1 = fexp2(L[1] + dbv - lseA[1]);
                float e2 = fexp2(L[2] + dbv - lseA[2]);
                float e3 = fexp2(L[3] + dbv - lseA[3]);
                pA0 = cvt_pk_bf16(e0, e1);
                pA1 = cvt_pk_bf16(e2, e3);
            }
            // strip B (or zeros)
            unsigned pB0 = 0u, pB1 = 0u;
            if (bval) {
                f32x4 L = {0.f, 0.f, 0.f, 0.f};
                L = mfma_split(faB, fb, L);
                float e0 = fexp2(L[0] + dbv - lseB[0]);
                float e1 = fexp2(L[1] + dbv - lseB[1]);
                float e2 = fexp2(L[2] + dbv - lseB[2]);
                float e3 = fexp2(L[3] + dbv - lseB[3]);
                pB0 = cvt_pk_bf16(e0, e1);
                pB1 = cvt_pk_bf16(e2, e3);
            }
            // in-register transpose to A-layout: A[m=s][k=t], k = q*8 + j
            xpose_quads(pA0, pA1, pB0, pB1);
            uint4v hv = {pA0, pA1, pB0, pB1};
            bf16x8 a2h = __builtin_bit_cast(bf16x8, hv);
#pragma unroll
            for (int ct = 0; ct < 2; ++ct)
                acc[si][ct] = mfma16(a2h, b2h[ct], acc[si][ct]);
        }
    }
    __syncthreads();   // all X32 reads done; safe to alias

    // ---- store x_del into reused LDS (float, stride XDS=28, 16B-aligned rows) ----
    float* fbse = (float*)&X32[0];
    float* xdelf = fbse;            // x_del: [0 .. 5600)
    float* pbuf  = fbse;            // R0 [0..1600): p_s, later p4
    float* r1    = fbse + 1600;     // R1 [1600..3200): p1, later h
    float* r2    = fbse + 3200;     // R2 [3200..4800): p2
#pragma unroll
    for (int si = 0; si < 4; ++si) {
        const int sv = wid + 4 * si;
        if (sv >= NSTILE) continue;
#pragma unroll
        for (int ct = 0; ct < 2; ++ct) {
            const int c = ct * 16 + n;
            if (c < C_) {
#pragma unroll
                for (int r = 0; r < 4; ++r) {
                    const int s = sv * 16 + q * 4 + r;
                    if (s < S_) xdelf[s * XDS + c] = acc[si][ct][r];
                }
            }
        }
    }
    __syncthreads();

    // ---- u / bgate epilogue: load row into regs, barrier, then write p into R0 ----
    {
        float a[24], a24 = 0.f;
        const bool act = tid < S_;
        if (act) {
            const f32x4* ar = (const f32x4*)&xdelf[tid * XDS];
#pragma unroll
            for (int k = 0; k < 6; ++k) *(f32x4*)&a[k * 4] = ar[k];
            a24 = xdelf[tid * XDS + 24];
        }
        __syncthreads();              // all x_del rows consumed; R0 write is safe
        if (act) {
            const int s = tid;
#pragma unroll
            for (int h = 0; h < H_; ++h) {
                float uu = fmaf(a24, U_W[h * C_ + 24], U_b[h]);
                float bb = fmaf(a24, B_W[h * C_ + 24], B_b[h]);
#pragma unroll
                for (int i = 0; i < 24; ++i) {
                    uu = fmaf(a[i], U_W[h * C_ + i], uu);
                    bb = fmaf(a[i], B_W[h * C_ + i], bb);
                }
                float sg_ = 1.0f / (1.0f + __expf(-bb));
                pbuf[s * H_ + h] = uu * sg_;
            }
        }
    }
    __syncthreads();

    // ---- linear recurrence h_s = A h_{s-1} + p_s via 8-step parallel prefix ----
    // p1 = A p[s-1] + p[s]   R0 -> R1
    for (int i2 = tid; i2 < S_ * H_; i2 += 256) {
        const int s = i2 >> 3, i = i2 & 7;
        float v = pbuf[i2];
        if (s > 0) {
            const float* pm = &pbuf[(s - 1) * H_];
#pragma unroll
            for (int j = 0; j < H_; ++j) v = fmaf(A_W[i * H_ + j], pm[j], v);
        }
        r1[i2] = v;
    }
    __syncthreads();
    // p2 = A^2 p1[s-2] + p1[s]   R1 -> R2
    for (int i2 = tid; i2 < S_ * H_; i2 += 256) {
        const int s = i2 >> 3, i = i2 & 7;
        float v = r1[i2];
        if (s > 1) {
            const float* pm = &r1[(s - 2) * H_];
#pragma unroll
            for (int j = 0; j < H_; ++j) v = fmaf(A2g[i * H_ + j], pm[j], v);
        }
        r2[i2] = v;
    }
    __syncthreads();
    // p4 = A^4 p2[s-4] + p2[s]   R2 -> R0
    for (int i2 = tid; i2 < S_ * H_; i2 += 256) {
        const int s = i2 >> 3, i = i2 & 7;
        float v = r2[i2];
        if (s > 3) {
            const float* pm = &r2[(s - 4) * H_];
#pragma unroll
            for (int j = 0; j < H_; ++j) v = fmaf(A4g[i * H_ + j], pm[j], v);
        }
        pbuf[i2] = v;
    }
    __syncthreads();
    // 8 independent chains (s mod 8) of 25 steps; 64 lanes of wave 0; h -> R1
    if (tid < 64) {
        const int r = tid >> 3, i = tid & 7;
        float A8r[H_];
#pragma unroll
        for (int j = 0; j < H_; ++j) A8r[j] = A8g[i * H_ + j];
        float h = 0.f;
        for (int k = 0; k < 25; ++k) {
            const int s = 8 * k + r;
            float v = pbuf[s * H_ + i];
#pragma unroll
            for (int j = 0; j < H_; ++j) v = fmaf(A8r[j], __shfl(h, j, 8), v);
            h = v;
            r1[s * H_ + i] = h;
        }
    }
    __syncthreads();

    // ---- out[b,s,c] = hs[s]·out_W[c,:] + out_b[c] (vectorized loads, h in R1) ----
    float* ob_ptr = out + (size_t)b * (S_ * C_);
    for (int i = tid; i < S_ * C_; i += 256) {
        int s = i / C_, c = i - s * C_;
        const f32x4* pr = (const f32x4*)&r1[s * H_];
        const f32x4* wr = (const f32x4*)&out_W[c * H_];
        f32x4 h0 = pr[0], h1 = pr[1];
        f32x4 w0 = wr[0], w1 = wr[1];
        float v = out_b[c];
        v = fmaf(h0[0], w0[0], v);
        v = fmaf(h0[1], w0[1], v);
        v = fmaf(h0[2], w0[2], v);
        v = fmaf(h0[3], w0[3], v);
        v = fmaf(h1[0], w1[0], v);
        v = fmaf(h1[1], w1[1], v);
        v = fmaf(h1[2], w1[2], v);
        v = fmaf(h1[3], w1[3], v);
        ob_ptr[i] = v;
    }
}

extern "C" void kernel_launch(void* const* d_in, const int* in_sizes, int n_in,
                              void* d_out, int out_size, void* d_ws, size_t ws_size,
                              hipStream_t stream) {
    const float* x       = (const float*)d_in[0];
    const float* delay_W = (const float*)d_in[1];
    const float* delay_b = (const float*)d_in[2];
    const float* U_W     = (const float*)d_in[3];
    const float* U_b     = (const float*)d_in[4];
    const float* A_W     = (const float*)d_in[5];
    const float* B_W     = (const float*)d_in[6];
    const float* B_b     = (const float*)d_in[7];
    const float* out_W   = (const float*)d_in[8];
    const float* out_b   = (const float*)d_in[9];
    float* out = (float*)d_out;
    unsigned* ws = (unsigned*)d_ws;   // (2*3328 + 192) dwords = 27,392 B

    prep_w_kernel<<<4, 256, 0, stream>>>(delay_W, A_W, ws);
    ssm_syn_delay_kernel<<<NB, 256, 0, stream>>>(
        x, ws, delay_b, U_W, U_b, A_W, B_W, B_b, out_W, out_b, out);
}